// Round 2
// baseline (21.208 us; speedup 1.0000x reference)
//
#include <hip/hip_runtime.h>

// Problem constants: B=128, P=2048, N=256, D=2
constexpr int B      = 128;
constexpr int P      = 2048;
constexpr int N      = 256;
constexpr int TPB    = 256;   // 4 waves
constexpr int CPW    = 4;     // centers per wave (exclusively owned)
constexpr int NPB    = 16;    // centers per block = 4 waves * 4
constexpr int PITER  = P / 64;     // 32 p-iterations per lane
constexpr int GROUPS = PITER / 2;  // 16 paired groups

__device__ __forceinline__ float rdfl(float v) {
    // Force wave-uniform value into an SGPR.
    return __int_as_float(__builtin_amdgcn_readfirstlane(__float_as_int(v)));
}

__global__ __launch_bounds__(TPB, 8)
void SLayerRational_43190191128606_kernel(
    const float* __restrict__ batch,      // (B, P, 2)
    const float* __restrict__ not_dummy,  // (B, P)
    const float* __restrict__ centers,    // (N, 2)
    const float* __restrict__ sharpness,  // (N, 2)
    const float* __restrict__ exponent,   // (1,)
    float* __restrict__ out)              // (B, N)
{
    const int b    = blockIdx.x >> 4;
    const int n0   = (blockIdx.x & 15) * NPB;
    const int wave = threadIdx.x >> 6;
    const int lane = threadIdx.x & 63;
    const int nw   = n0 + wave * CPW;     // first center this wave owns

    // Wave-uniform center params -> SGPRs
    float c0[CPW], c1[CPW], a0[CPW], a1[CPW];
#pragma unroll
    for (int c = 0; c < CPW; ++c) {
        c0[c] = rdfl(centers[(nw + c) * 2 + 0]);
        c1[c] = rdfl(centers[(nw + c) * 2 + 1]);
        a0[c] = rdfl(fabsf(sharpness[(nw + c) * 2 + 0]));
        a1[c] = rdfl(fabsf(sharpness[(nw + c) * 2 + 1]));
    }
    const float e = exponent[0];

    float acc[CPW];
#pragma unroll
    for (int c = 0; c < CPW; ++c) acc[c] = 0.0f;

    const float2* bb = reinterpret_cast<const float2*>(batch) + (size_t)b * P;
    const float*  nd = not_dummy + (size_t)b * P;

    if (e == 1.0f) {
        // Fast path. Pair two p-points per rcp:
        //   1/u_a + 1/u_b = (w_a*u_b + w_b*u_a) / (u_a*u_b),  u = 1 + s
#pragma unroll 4
        for (int g = 0; g < GROUPS; ++g) {
            const int p = g * 128 + lane;
            const float2 xa = bb[p];
            const float2 xb = bb[p + 64];
            const float  wa = nd[p];
            const float  wb = nd[p + 64];
#pragma unroll
            for (int c = 0; c < CPW; ++c) {
                const float d0a = c0[c] - xa.x;
                const float d1a = c1[c] - xa.y;
                const float ua  = fmaf(fabsf(d0a), a0[c],
                                   fmaf(fabsf(d1a), a1[c], 1.0f));
                const float d0b = c0[c] - xb.x;
                const float d1b = c1[c] - xb.y;
                const float ub  = fmaf(fabsf(d0b), a0[c],
                                   fmaf(fabsf(d1b), a1[c], 1.0f));
                float num = wa * ub;
                num = fmaf(wb, ua, num);
                const float den = ua * ub;
                const float r   = __builtin_amdgcn_rcpf(den);
                acc[c] = fmaf(num, r, acc[c]);
            }
        }
    } else {
        // General path: r = w / (1 + s^e)
        for (int it = 0; it < PITER; ++it) {
            const int p = it * 64 + lane;
            const float2 x = bb[p];
            const float  w = nd[p];
#pragma unroll
            for (int c = 0; c < CPW; ++c) {
                const float s = fmaf(fabsf(c0[c] - x.x), a0[c],
                                     fabsf(c1[c] - x.y) * a1[c]);
                acc[c] += w / (1.0f + powf(s, e));
            }
        }
    }

    // Wave-local tree reduction; no LDS, no __syncthreads needed.
#pragma unroll
    for (int c = 0; c < CPW; ++c) {
#pragma unroll
        for (int off = 32; off > 0; off >>= 1)
            acc[c] += __shfl_down(acc[c], off, 64);
    }

    if (lane == 0) {
#pragma unroll
        for (int c = 0; c < CPW; ++c)
            out[b * N + nw + c] = acc[c];
    }
}

extern "C" void kernel_launch(void* const* d_in, const int* in_sizes, int n_in,
                              void* d_out, int out_size, void* d_ws, size_t ws_size,
                              hipStream_t stream) {
    const float* batch     = (const float*)d_in[0];
    const float* not_dummy = (const float*)d_in[1];
    const float* centers   = (const float*)d_in[2];
    const float* sharpness = (const float*)d_in[3];
    const float* exponent  = (const float*)d_in[4];
    float* out = (float*)d_out;

    const int blocks = B * (N / NPB);  // 2048
    SLayerRational_43190191128606_kernel<<<blocks, TPB, 0, stream>>>(
        batch, not_dummy, centers, sharpness, exponent, out);
}